// Round 4
// baseline (66.204 us; speedup 1.0000x reference)
//
#include <hip/hip_runtime.h>
#include <math.h>

namespace {
constexpr int N_ = 2048;
constexpr int D_ = 128;
constexpr int K_ = 8;
constexpr int M_ = 64;
constexpr float JIT = 1e-5f;
constexpr float L2E = 1.4426950408889634f;
constexpr float LN2 = 0.6931471805599453f;

// ws layout (float offsets)
constexpr int OFF_ARR2 = 0;                   // N*16  : per-n [a[8], ib2s[8]]
constexpr int OFF_C2   = N_ * 16;             // N     : prod rsqrt(2s2+1)
constexpr int OFF_P2P  = N_ * 17;             // 16*4096 : psi2 partial sums
constexpr int OFF_P1Y  = N_ * 17 + 16 * 4096; // 8*64    : Psi1^T Y partials
}

struct F8 { float f[8]; };

__device__ __forceinline__ float f4e(float4 v, int e) {
  return (e == 0) ? v.x : (e == 1) ? v.y : (e == 2) ? v.z : v.w;
}

// ---------------------------------------------------------------------------
// Kernel A: per-n statistics + Psi1^T Y partials (fused; arr1/cy stay in LDS)
// 8 blocks x 256 threads; block b owns n in [256b, 256b+256).
// ---------------------------------------------------------------------------
__global__ __launch_bounds__(256) void vdmgp_prep_p1y(
    const float* __restrict__ X, const float* __restrict__ Y,
    const float* __restrict__ qmu, const float* __restrict__ qcov,
    const float* __restrict__ Z, float* __restrict__ ws) {
  __shared__ float smu[D_ * K_];   // transposed: [d][k]
  __shared__ float scov[D_ * K_];
  __shared__ float sa1[256 * 16];  // per-n [a[8], ib1s[8]]
  __shared__ float scy[256];
  __shared__ float red[256];
  const int tid = threadIdx.x;
  for (int idx = tid; idx < K_ * D_; idx += 256) {
    int k = idx >> 7, d = idx & 127;
    smu[d * K_ + k]  = qmu[idx];
    scov[d * K_ + k] = qcov[idx];
  }
  __syncthreads();

  const int n = blockIdx.x * 256 + tid;
  float a[K_], s2[K_];
#pragma unroll
  for (int k = 0; k < K_; k++) { a[k] = 0.f; s2[k] = 0.f; }

  const float4* xrow = reinterpret_cast<const float4*>(X + n * D_);
  for (int dq = 0; dq < D_ / 4; dq++) {
    float4 xv = xrow[dq];
    float xs[4] = {xv.x, xv.y, xv.z, xv.w};
#pragma unroll
    for (int t = 0; t < 4; t++) {
      const int d = dq * 4 + t;
      const float x = xs[t];
      const float xx = x * x;
      F8 mu = *reinterpret_cast<const F8*>(&smu[d * K_]);
      F8 cv = *reinterpret_cast<const F8*>(&scov[d * K_]);
#pragma unroll
      for (int k = 0; k < K_; k++) {
        a[k]  = fmaf(mu.f[k], x, a[k]);
        s2[k] = fmaf(cv.f[k], xx, s2[k]);
      }
    }
  }

  float4 w2[4];
  float prod2 = 1.f, prod1 = 1.f;
#pragma unroll
  for (int k = 0; k < K_; k++) {
    const float b2 = 2.f * s2[k] + 1.f;
    const float b1 = 1.f + s2[k];
    reinterpret_cast<float*>(w2)[k]     = a[k];
    reinterpret_cast<float*>(w2)[8 + k] = L2E / b2;   // exp(-t^2/b2) = exp2(-t^2*this)
    sa1[tid * 16 + k]     = a[k];
    sa1[tid * 16 + 8 + k] = 0.5f * L2E / b1;          // exp(-0.5 t^2/b1)
    prod2 *= rsqrtf(b2);
    prod1 *= rsqrtf(b1);
  }
  float4* arr2q = reinterpret_cast<float4*>(ws + OFF_ARR2 + n * 16);
#pragma unroll
  for (int e = 0; e < 4; e++) arr2q[e] = w2[e];
  (ws + OFF_C2)[n] = prod2;
  scy[tid] = prod1 * Y[n];
  __syncthreads();

  // Psi1^T Y over this block's 256 n's
  const int m = tid & 63;
  const int stripe = tid >> 6;
  float zm[K_];
#pragma unroll
  for (int k = 0; k < K_; k++) zm[k] = Z[m * K_ + k];

  float acc = 0.f;
  for (int t = 0; t < 64; t++) {
    const int nl = stripe * 64 + t;
    const F8 av = *reinterpret_cast<const F8*>(&sa1[nl * 16]);
    const F8 ib = *reinterpret_cast<const F8*>(&sa1[nl * 16 + 8]);
    float s = 0.f;
#pragma unroll
    for (int k = 0; k < K_; k++) {
      const float d = av.f[k] - zm[k];
      s = fmaf(d * d, ib.f[k], s);
    }
    acc = fmaf(scy[nl], exp2f(-s), acc);
  }
  red[tid] = acc;
  __syncthreads();
  if (tid < 64)
    (ws + OFF_P1Y)[blockIdx.x * 64 + tid] =
        red[tid] + red[64 + tid] + red[128 + tid] + red[192 + tid];
}

// ---------------------------------------------------------------------------
// Kernel B: psi2 partial sums over n-chunks. grid (16 pair-blocks, 16 chunks).
// ---------------------------------------------------------------------------
__global__ __launch_bounds__(256) void vdmgp_psi2(
    const float* __restrict__ Z, const float* __restrict__ ws,
    float* __restrict__ part) {
  __shared__ float sa[128 * 16];
  __shared__ float sc[128];
  const int tid = threadIdx.x;
  const int pair = blockIdx.x * 256 + tid;
  const int i = pair >> 6, j = pair & 63;

  float zb[K_];
#pragma unroll
  for (int k = 0; k < K_; k++) zb[k] = 0.5f * (Z[i * K_ + k] + Z[j * K_ + k]);

  const int nbase = blockIdx.y * 128;
  const float4* src = reinterpret_cast<const float4*>(ws + OFF_ARR2 + nbase * 16);
  float4* dst = reinterpret_cast<float4*>(sa);
  for (int idx = tid; idx < 128 * 4; idx += 256) dst[idx] = src[idx];
  if (tid < 128) sc[tid] = (ws + OFF_C2)[nbase + tid];
  __syncthreads();

  float acc = 0.f;
  for (int nl = 0; nl < 128; nl++) {
    const F8 av = *reinterpret_cast<const F8*>(&sa[nl * 16]);
    const F8 ib = *reinterpret_cast<const F8*>(&sa[nl * 16 + 8]);
    float s = 0.f;
#pragma unroll
    for (int k = 0; k < K_; k++) {
      const float t = av.f[k] - zb[k];
      s = fmaf(t * t, ib.f[k], s);
    }
    acc = fmaf(sc[nl], exp2f(-s), acc);
  }
  part[blockIdx.y * 4096 + pair] = acc;
}

// ---------------------------------------------------------------------------
// Kernel C: reduce partials (lft folded) + two ROLLED rotating-register
// 2x2-pivot symmetric sweeps (wave0: Kuu, wave1: KuPsi2); waves 2/3: YY+KL.
// Invariant at start of step s: reg[r] = A_cur[(r + 2s) & 63][lane].
// ---------------------------------------------------------------------------
__global__ __launch_bounds__(256, 1) void vdmgp_final(
    const float* __restrict__ Y,
    const float* __restrict__ qmu, const float* __restrict__ qcov,
    const float* __restrict__ Z,
    const float* __restrict__ sfp, const float* __restrict__ nvp,
    const float* __restrict__ ws, float* __restrict__ out) {
  __shared__ float P2s[M_][M_];                // psi2 (left folded), symmetric
  __shared__ float zl[M_][9];
  __shared__ float pysL[M_];
  __shared__ __align__(16) float rowbuf[2][2][M_];  // [wave][A/B][pos]
  __shared__ float scal[8];

  const int tid = threadIdx.x;
  const int lane = tid & 63;
  const int wave = tid >> 6;
  const float sf = sfp[0];
  const float s2v = nvp[0];

  // ---- phase 0 ----
  for (int idx = tid; idx < M_ * K_; idx += 256) zl[idx >> 3][idx & 7] = Z[idx];
  if (tid < M_) {
    const float* p1y = ws + OFF_P1Y;
    float s = 0.f;
#pragma unroll
    for (int b = 0; b < 8; b++) s += p1y[b * M_ + tid];
    pysL[tid] = sf * s;
  }
  __syncthreads();

  // reduce the 16 psi2 partials, fold `left`
  const float4* part4 = reinterpret_cast<const float4*>(ws + OFF_P2P);
  const float sf2 = sf * sf;
#pragma unroll
  for (int g = 0; g < 4; g++) {
    const int idx4 = g * 256 + tid;
    float4 acc = {0.f, 0.f, 0.f, 0.f};
#pragma unroll
    for (int c = 0; c < 16; c++) {
      const float4 v = part4[c * 1024 + idx4];
      acc.x += v.x; acc.y += v.y; acc.z += v.z; acc.w += v.w;
    }
    const int i = idx4 >> 4;
    const int j0 = (idx4 & 15) * 4;
    float o[4];
#pragma unroll
    for (int e = 0; e < 4; e++) {
      const int j = j0 + e;
      float sq = 0.f;
#pragma unroll
      for (int k = 0; k < K_; k++) {
        const float dd = zl[i][k] - zl[j][k];
        sq = fmaf(dd, dd, sq);
      }
      o[e] = sf2 * exp2f(-0.25f * L2E * sq) * f4e(acc, e);
    }
    *reinterpret_cast<float4*>(&P2s[i][j0]) = make_float4(o[0], o[1], o[2], o[3]);
  }
  __syncthreads();

  // ---- phase 1 ----
  if (wave < 2) {
    const bool isA2 = (wave == 1);
    float zj[K_];
#pragma unroll
    for (int k = 0; k < K_; k++) zj[k] = zl[lane][k];

    float reg[M_];
#pragma unroll
    for (int i = 0; i < M_; i++) {
      float sq = 0.f;
#pragma unroll
      for (int k = 0; k < K_; k++) { const float dd = zl[i][k] - zj[k]; sq = fmaf(dd, dd, sq); }
      const float jit = (i == lane) ? JIT : 0.f;
      const float kj = exp2f(-0.5f * L2E * sq) + jit;      // Kuu + jitter
      reg[i] = isA2 ? fmaf(s2v, kj, P2s[i][lane] + jit) : kj;
    }

    // rolled rotating-register 2x2 symmetric sweep: reg -> (-A^{-1}) col lane
    float ld = 0.f;
    float* rbA = rowbuf[wave][0];
    float* rbB = rowbuf[wave][1];
    const float4* A4 = reinterpret_cast<const float4*>(rbA);
    const float4* B4 = reinterpret_cast<const float4*>(rbB);
    for (int s = 0; s < 32; ++s) {
      const int p = 2 * s;
      const int pos = (lane - p - 2) & 63;   // pre-shifted so reads are static
      rbA[pos] = reg[0];                     // row p   (== col p by symmetry)
      rbB[pos] = reg[1];                     // row p+1
      // per-wave LDS is in-order; compiler inserts the lgkmcnt waits.
      const float P00 = rbA[62];             // A[p][p]
      const float P01 = rbA[63];             // A[p][p+1]
      const float P11 = rbB[63];             // A[p+1][p+1]
      const float det = fmaf(P00, P11, -P01 * P01);
      const float idet = __builtin_amdgcn_rcpf(det);
      ld += __log2f(det);
      const float Pi00 =  P11 * idet;
      const float Pi01 = -P01 * idet;
      const float Pi11 =  P00 * idet;

      const bool isp = (lane == p), isq = (lane == p + 1);
      const float a0 = reg[0], a1 = reg[1];
      const float w0 = isp ? Pi00 : (isq ? Pi01 : fmaf(Pi00, a0, Pi01 * a1));
      const float w1 = isp ? Pi01 : (isq ? Pi11 : fmaf(Pi01, a0, Pi11 * a1));
      const float t0 = isp ? (1.f - w0) : (isq ? -w0 : w0);
      const float t1 = isq ? (1.f - w1) : (isp ? -w1 : w1);
      const float f0 = (isp || isq) ? -w0 : w0;
      const float f1 = (isp || isq) ? -w1 : w1;

      // reg[r] = old reg[r+2] - t0*rowA[r] - t1*rowB[r]   (buffer pos r
      // holds true-row r+2+p); shift-by-2 folded into the update.
#pragma unroll
      for (int q = 0; q < 15; ++q) {
        const float4 va = A4[q], vb = B4[q];
        reg[4 * q + 0] = fmaf(-t1, vb.x, fmaf(-t0, va.x, reg[4 * q + 2]));
        reg[4 * q + 1] = fmaf(-t1, vb.y, fmaf(-t0, va.y, reg[4 * q + 3]));
        reg[4 * q + 2] = fmaf(-t1, vb.z, fmaf(-t0, va.z, reg[4 * q + 4]));
        reg[4 * q + 3] = fmaf(-t1, vb.w, fmaf(-t0, va.w, reg[4 * q + 5]));
      }
      {
        const float4 va = A4[15], vb = B4[15];
        reg[60] = fmaf(-t1, vb.x, fmaf(-t0, va.x, reg[62]));
        reg[61] = fmaf(-t1, vb.y, fmaf(-t0, va.y, reg[63]));
      }
      reg[62] = f0;   // true row p   -> rot pos 62
      reg[63] = f1;   // true row p+1 -> rot pos 63
    }
    // after 32 steps rotation = 64 == 0: reg[i] = (-A^{-1})[i][lane]

    float local = 0.f;
    if (!isA2) {
#pragma unroll
      for (int i = 0; i < M_; i++) local = fmaf(reg[i], P2s[i][lane], local);
    } else {
#pragma unroll
      for (int i = 0; i < M_; i++) local = fmaf(reg[i], pysL[i], local);
      local *= pysL[lane];
    }
#pragma unroll
    for (int off = 32; off > 0; off >>= 1) local += __shfl_down(local, off, 64);
    if (lane == 0) {
      scal[4 + 2 * wave] = LN2 * ld;   // [4]=logdet(Kuu), [6]=logdet(KuPsi2)
      scal[5 + 2 * wave] = -local;     // [5]=trace,       [7]=quad
    }
  } else {
    const int w = wave - 2;
    float yy = 0.f;
#pragma unroll
    for (int t = 0; t < 16; t++) {
      const float y = Y[w * 1024 + t * 64 + lane];
      yy = fmaf(y, y, yy);
    }
#pragma unroll
    for (int off = 32; off > 0; off >>= 1) yy += __shfl_down(yy, off, 64);
    if (lane == 0) scal[w] = yy;

    const int r = lane >> 4;
    const int k = w * 4 + r;
    const int d0 = (lane & 15) * 8;
    float slog = 0.f, srow = 0.f;
#pragma unroll
    for (int t = 0; t < 8; t++) {
      const float qc = qcov[k * D_ + d0 + t];
      const float qm = qmu[k * D_ + d0 + t];
      slog += logf(qc);
      srow += qc + qm * qm;
    }
#pragma unroll
    for (int off = 8; off > 0; off >>= 1) {
      slog += __shfl_down(slog, off, 16);
      srow += __shfl_down(srow, off, 16);
    }
    float klr = ((lane & 15) == 0)
        ? (slog - (float)D_ * logf(srow) + (float)D_ * logf((float)D_)) : 0.f;
#pragma unroll
    for (int off = 32; off > 0; off >>= 1) klr += __shfl_down(klr, off, 64);
    if (lane == 0) scal[2 + w] = klr;
  }
  __syncthreads();

  if (tid == 0) {
    const float YY = scal[0] + scal[1];
    const float KL = scal[2] + scal[3];
    const float ld1 = scal[4], tr = scal[5], ld2 = scal[6], quad = scal[7];
    const float inv = 1.0f / s2v;
    const float F1 = -(float)N_ * 1.8378770664093453f      // N*log(2*pi)
                   - (float)(N_ - M_) * logf(s2v)
                   + (ld1 - ld2)
                   - YY * inv
                   + quad * inv
                   - (float)N_ * sf * sf * inv
                   + tr * inv;
    out[0] = 0.5f * (F1 + KL);
  }
}

extern "C" void kernel_launch(void* const* d_in, const int* in_sizes, int n_in,
                              void* d_out, int out_size, void* d_ws, size_t ws_size,
                              hipStream_t stream) {
  const float* X    = (const float*)d_in[0];
  const float* Y    = (const float*)d_in[1];
  const float* qmu  = (const float*)d_in[2];
  const float* qcov = (const float*)d_in[3];
  const float* Z    = (const float*)d_in[4];
  const float* sfp  = (const float*)d_in[5];
  const float* nvp  = (const float*)d_in[6];
  float* ws  = (float*)d_ws;
  float* out = (float*)d_out;

  vdmgp_prep_p1y<<<8, 256, 0, stream>>>(X, Y, qmu, qcov, Z, ws);
  vdmgp_psi2<<<dim3(16, 16), 256, 0, stream>>>(Z, ws, ws + OFF_P2P);
  vdmgp_final<<<1, 256, 0, stream>>>(Y, qmu, qcov, Z, sfp, nvp, ws, out);
}

// Round 5
// 62.923 us; speedup vs baseline: 1.0521x; 1.0521x over previous
//
#include <hip/hip_runtime.h>
#include <math.h>

namespace {
constexpr int N_ = 2048;
constexpr int D_ = 128;
constexpr int K_ = 8;
constexpr int M_ = 64;
constexpr float JIT = 1e-5f;
constexpr float L2E = 1.4426950408889634f;
constexpr float LN2 = 0.6931471805599453f;

// ws layout (float offsets)
constexpr int OFF_P2P = 0;                 // 16*4096 : psi2 partial sums
constexpr int OFF_P1Y = 16 * 4096;         // 16*64   : Psi1^T Y partials
constexpr int OFF_KUI = OFF_P1Y + 1024;    // 4096    : -Kuu^{-1} row-major
constexpr int OFF_SC  = OFF_KUI + 4096;    // 3       : YY, KL, logdet(Kuu)
}

struct F8 { float f[8]; };

__device__ __forceinline__ float f4e(float4 v, int e) {
  return (e == 0) ? v.x : (e == 1) ? v.y : (e == 2) ? v.z : v.w;
}

// per-n stats: a[k] = q_mu[k]·x_n, s2[k] = q_cov[k]·(x_n^2); smu/scov are [d][k]
__device__ __forceinline__ void compute_stats(
    const float* __restrict__ X, const float* smu, const float* scov,
    int n, float* a, float* s2) {
#pragma unroll
  for (int k = 0; k < K_; k++) { a[k] = 0.f; s2[k] = 0.f; }
  const float4* xrow = reinterpret_cast<const float4*>(X + n * D_);
  for (int dq = 0; dq < D_ / 4; dq++) {
    float4 xv = xrow[dq];
    float xs[4] = {xv.x, xv.y, xv.z, xv.w};
#pragma unroll
    for (int t = 0; t < 4; t++) {
      const int d = dq * 4 + t;
      const float x = xs[t];
      const float xx = x * x;
      F8 mu = *reinterpret_cast<const F8*>(&smu[d * K_]);
      F8 cv = *reinterpret_cast<const F8*>(&scov[d * K_]);
#pragma unroll
      for (int k = 0; k < K_; k++) {
        a[k]  = fmaf(mu.f[k], x, a[k]);
        s2[k] = fmaf(cv.f[k], xx, s2[k]);
      }
    }
  }
}

// unrolled 2x2-block symmetric sweep: reg (column `lane` of SPD A) ->
// column of (-A^{-1}); returns log2(det A). rowbuf is [parity*2 + A/B][64].
__device__ __forceinline__ float sweep2x2(float* reg, float (*rowbuf)[M_], int lane) {
  float ld = 0.f;
#pragma unroll
  for (int p = 0; p < M_; p += 2) {
    const int par = (p >> 1) & 1;
    float* rbA = rowbuf[par * 2 + 0];
    float* rbB = rowbuf[par * 2 + 1];
    rbA[lane] = reg[p];
    rbB[lane] = reg[p + 1];
    float4 ra[16], rb[16];
    const float4* rbAq = reinterpret_cast<const float4*>(rbA);
    const float4* rbBq = reinterpret_cast<const float4*>(rbB);
#pragma unroll
    for (int q = 0; q < 16; q++) { ra[q] = rbAq[q]; rb[q] = rbBq[q]; }

    const float P00 = f4e(ra[p >> 2], p & 3);
    const float P01 = f4e(ra[(p + 1) >> 2], (p + 1) & 3);
    const float P11 = f4e(rb[(p + 1) >> 2], (p + 1) & 3);
    const float det = fmaf(P00, P11, -P01 * P01);
    const float idet = __builtin_amdgcn_rcpf(det);
    ld += __log2f(det);
    const float Pi00 =  P11 * idet;
    const float Pi01 = -P01 * idet;
    const float Pi11 =  P00 * idet;

    const bool isp = (lane == p), isq = (lane == p + 1);
    const float a0 = reg[p], a1 = reg[p + 1];
    const float w0 = isp ? Pi00 : (isq ? Pi01 : fmaf(Pi00, a0, Pi01 * a1));
    const float w1 = isp ? Pi01 : (isq ? Pi11 : fmaf(Pi01, a0, Pi11 * a1));
    const float t0 = isp ? (1.f - w0) : (isq ? -w0 : w0);
    const float t1 = isq ? (1.f - w1) : (isp ? -w1 : w1);
    const float f0 = (isp || isq) ? -w0 : w0;
    const float f1 = (isp || isq) ? -w1 : w1;
#pragma unroll
    for (int q = 0; q < 16; q++) {
      const float4 va = ra[q], vb = rb[q];
      reg[4 * q + 0] = fmaf(-t1, vb.x, fmaf(-t0, va.x, reg[4 * q + 0]));
      reg[4 * q + 1] = fmaf(-t1, vb.y, fmaf(-t0, va.y, reg[4 * q + 1]));
      reg[4 * q + 2] = fmaf(-t1, vb.z, fmaf(-t0, va.z, reg[4 * q + 2]));
      reg[4 * q + 3] = fmaf(-t1, vb.w, fmaf(-t0, va.w, reg[4 * q + 3]));
    }
    reg[p] = f0;
    reg[p + 1] = f1;
  }
  return ld;
}

// ---------------------------------------------------------------------------
// K1 "mega": grid (16, 18).
//   by==0, bx==0 : scalar block — Kuu^{-1} sweep (wave0), YY (wave1), KL (wave2)
//   by in [1,17) : psi2 chunk (by-1), with in-block stats recompute
//   by==17       : Psi1^T Y chunk (bx), with in-block stats recompute
// ---------------------------------------------------------------------------
__global__ __launch_bounds__(256, 1) void vdmgp_mega(
    const float* __restrict__ X, const float* __restrict__ Y,
    const float* __restrict__ qmu, const float* __restrict__ qcov,
    const float* __restrict__ Z, float* __restrict__ ws) {
  __shared__ float smu[D_ * K_];
  __shared__ float scov[D_ * K_];
  __shared__ float sa[128 * 16];
  __shared__ float sc[128];
  __shared__ float red[256];
  __shared__ float zl[M_][9];
  __shared__ __align__(16) float rowbuf[4][M_];

  const int tid = threadIdx.x;
  const int bx = blockIdx.x, by = blockIdx.y;

  if (by == 0) {
    if (bx != 0) return;
    for (int idx = tid; idx < M_ * K_; idx += 256) zl[idx >> 3][idx & 7] = Z[idx];
    __syncthreads();
    const int lane = tid & 63;
    const int wave = tid >> 6;
    if (wave == 0) {
      float zj[K_];
#pragma unroll
      for (int k = 0; k < K_; k++) zj[k] = zl[lane][k];
      float reg[M_];
#pragma unroll
      for (int i = 0; i < M_; i++) {
        float sq = 0.f;
#pragma unroll
        for (int k = 0; k < K_; k++) { const float dd = zl[i][k] - zj[k]; sq = fmaf(dd, dd, sq); }
        reg[i] = exp2f(-0.5f * L2E * sq) + ((i == lane) ? JIT : 0.f);
      }
      const float ld = sweep2x2(reg, rowbuf, lane);
#pragma unroll
      for (int i = 0; i < M_; i++) ws[OFF_KUI + i * 64 + lane] = reg[i];
      if (lane == 0) ws[OFF_SC + 2] = LN2 * ld;
    } else if (wave == 1) {
      float yy = 0.f;
#pragma unroll
      for (int t = 0; t < 32; t++) {
        const float y = Y[t * 64 + lane];
        yy = fmaf(y, y, yy);
      }
#pragma unroll
      for (int off = 32; off > 0; off >>= 1) yy += __shfl_down(yy, off, 64);
      if (lane == 0) ws[OFF_SC + 0] = yy;
    } else if (wave == 2) {
      const int k = lane >> 3;
      const int d0 = (lane & 7) * 16;
      float slog = 0.f, srow = 0.f;
#pragma unroll
      for (int t = 0; t < 16; t++) {
        const float qc = qcov[k * D_ + d0 + t];
        const float qm = qmu[k * D_ + d0 + t];
        slog += logf(qc);
        srow += qc + qm * qm;
      }
#pragma unroll
      for (int off = 4; off > 0; off >>= 1) {
        slog += __shfl_down(slog, off, 8);
        srow += __shfl_down(srow, off, 8);
      }
      float klr = ((lane & 7) == 0)
          ? (slog - (float)D_ * logf(srow) + (float)D_ * logf((float)D_)) : 0.f;
      klr += __shfl_down(klr, 32, 64);
      klr += __shfl_down(klr, 16, 64);
      klr += __shfl_down(klr, 8, 64);
      if (lane == 0) ws[OFF_SC + 1] = klr;
    }
    return;
  }

  // stage q_mu/q_cov transposed (used by both remaining branches)
  for (int idx = tid; idx < K_ * D_; idx += 256) {
    int k = idx >> 7, d = idx & 127;
    smu[d * K_ + k]  = qmu[idx];
    scov[d * K_ + k] = qcov[idx];
  }
  __syncthreads();

  if (by <= 16) {
    // psi2 chunk
    const int chunk = by - 1;
    if (tid < 128) {
      const int n = chunk * 128 + tid;
      float a[K_], s2[K_];
      compute_stats(X, smu, scov, n, a, s2);
      float prod2 = 1.f;
#pragma unroll
      for (int k = 0; k < K_; k++) {
        const float b2 = 2.f * s2[k] + 1.f;
        sa[tid * 16 + k]     = a[k];
        sa[tid * 16 + 8 + k] = L2E / b2;
        prod2 *= rsqrtf(b2);
      }
      sc[tid] = prod2;
    }
    __syncthreads();

    const int pair = bx * 256 + tid;
    const int i = pair >> 6, j = pair & 63;
    float zb[K_];
#pragma unroll
    for (int k = 0; k < K_; k++) zb[k] = 0.5f * (Z[i * K_ + k] + Z[j * K_ + k]);

    float acc = 0.f;
    for (int nl = 0; nl < 128; nl++) {
      const F8 av = *reinterpret_cast<const F8*>(&sa[nl * 16]);
      const F8 ib = *reinterpret_cast<const F8*>(&sa[nl * 16 + 8]);
      float s = 0.f;
#pragma unroll
      for (int k = 0; k < K_; k++) {
        const float t = av.f[k] - zb[k];
        s = fmaf(t * t, ib.f[k], s);
      }
      acc = fmaf(sc[nl], exp2f(-s), acc);
    }
    (ws + OFF_P2P)[chunk * 4096 + pair] = acc;
    return;
  }

  // by == 17: Psi1^T Y chunk
  {
    const int chunk = bx;
    if (tid < 128) {
      const int n = chunk * 128 + tid;
      float a[K_], s2[K_];
      compute_stats(X, smu, scov, n, a, s2);
      float prod1 = 1.f;
#pragma unroll
      for (int k = 0; k < K_; k++) {
        const float b1 = 1.f + s2[k];
        sa[tid * 16 + k]     = a[k];
        sa[tid * 16 + 8 + k] = 0.5f * L2E / b1;
        prod1 *= rsqrtf(b1);
      }
      sc[tid] = prod1 * Y[n];
    }
    __syncthreads();

    const int m = tid & 63;
    const int stripe = tid >> 6;
    float zm[K_];
#pragma unroll
    for (int k = 0; k < K_; k++) zm[k] = Z[m * K_ + k];

    float acc = 0.f;
    for (int t = 0; t < 32; t++) {
      const int nl = stripe * 32 + t;
      const F8 av = *reinterpret_cast<const F8*>(&sa[nl * 16]);
      const F8 ib = *reinterpret_cast<const F8*>(&sa[nl * 16 + 8]);
      float s = 0.f;
#pragma unroll
      for (int k = 0; k < K_; k++) {
        const float d = av.f[k] - zm[k];
        s = fmaf(d * d, ib.f[k], s);
      }
      acc = fmaf(sc[nl], exp2f(-s), acc);
    }
    red[tid] = acc;
    __syncthreads();
    if (tid < 64)
      (ws + OFF_P1Y)[chunk * 64 + tid] =
          red[tid] + red[64 + tid] + red[128 + tid] + red[192 + tid];
  }
}

// ---------------------------------------------------------------------------
// K2 "final": 1 block. phase0: reduce psi2 partials (fold left) + pys.
// wave0: KuPsi2 sweep -> logdet2 + quad; wave1: trace vs precomputed Kuu^{-1}.
// ---------------------------------------------------------------------------
__global__ __launch_bounds__(256, 1) void vdmgp_final(
    const float* __restrict__ Z,
    const float* __restrict__ sfp, const float* __restrict__ nvp,
    const float* __restrict__ ws, float* __restrict__ out) {
  __shared__ float P2s[M_][M_];
  __shared__ float zl[M_][9];
  __shared__ float pysL[M_];
  __shared__ __align__(16) float rowbuf[4][M_];
  __shared__ float scal[8];

  const int tid = threadIdx.x;
  const int lane = tid & 63;
  const int wave = tid >> 6;
  const float sf = sfp[0];
  const float s2v = nvp[0];

  for (int idx = tid; idx < M_ * K_; idx += 256) zl[idx >> 3][idx & 7] = Z[idx];
  if (tid < M_) {
    const float* p1y = ws + OFF_P1Y;
    float s = 0.f;
#pragma unroll
    for (int c = 0; c < 16; c++) s += p1y[c * M_ + tid];
    pysL[tid] = sf * s;
  }
  __syncthreads();

  // reduce the 16 psi2 partial chunks, fold `left`
  const float4* part4 = reinterpret_cast<const float4*>(ws + OFF_P2P);
  const float sf2 = sf * sf;
#pragma unroll
  for (int g = 0; g < 4; g++) {
    const int idx4 = g * 256 + tid;
    float4 acc = {0.f, 0.f, 0.f, 0.f};
#pragma unroll
    for (int c = 0; c < 16; c++) {
      const float4 v = part4[c * 1024 + idx4];
      acc.x += v.x; acc.y += v.y; acc.z += v.z; acc.w += v.w;
    }
    const int i = idx4 >> 4;
    const int j0 = (idx4 & 15) * 4;
    float o[4];
#pragma unroll
    for (int e = 0; e < 4; e++) {
      const int j = j0 + e;
      float sq = 0.f;
#pragma unroll
      for (int k = 0; k < K_; k++) {
        const float dd = zl[i][k] - zl[j][k];
        sq = fmaf(dd, dd, sq);
      }
      o[e] = sf2 * exp2f(-0.25f * L2E * sq) * f4e(acc, e);
    }
    *reinterpret_cast<float4*>(&P2s[i][j0]) = make_float4(o[0], o[1], o[2], o[3]);
  }
  __syncthreads();

  if (wave == 0) {
    float zj[K_];
#pragma unroll
    for (int k = 0; k < K_; k++) zj[k] = zl[lane][k];
    float reg[M_];
#pragma unroll
    for (int i = 0; i < M_; i++) {
      float sq = 0.f;
#pragma unroll
      for (int k = 0; k < K_; k++) { const float dd = zl[i][k] - zj[k]; sq = fmaf(dd, dd, sq); }
      const float jit = (i == lane) ? JIT : 0.f;
      const float kj = exp2f(-0.5f * L2E * sq) + jit;
      reg[i] = fmaf(s2v, kj, P2s[i][lane] + jit);
    }
    const float ld2 = sweep2x2(reg, rowbuf, lane);
    float local = 0.f;
#pragma unroll
    for (int i = 0; i < M_; i++) local = fmaf(reg[i], pysL[i], local);
    local *= pysL[lane];
#pragma unroll
    for (int off = 32; off > 0; off >>= 1) local += __shfl_down(local, off, 64);
    if (lane == 0) {
      scal[6] = LN2 * ld2;
      scal[7] = -local;     // quad
    }
  } else if (wave == 1) {
    const float* kui = ws + OFF_KUI;   // holds -Kuu^{-1}
    float acc = 0.f;
#pragma unroll
    for (int i = 0; i < M_; i++) acc = fmaf(kui[i * 64 + lane], P2s[i][lane], acc);
#pragma unroll
    for (int off = 32; off > 0; off >>= 1) acc += __shfl_down(acc, off, 64);
    if (lane == 0) scal[5] = -acc;     // trace
  }
  __syncthreads();

  if (tid == 0) {
    const float YY  = ws[OFF_SC + 0];
    const float KL  = ws[OFF_SC + 1];
    const float ld1 = ws[OFF_SC + 2];
    const float tr = scal[5], ld2 = scal[6], quad = scal[7];
    const float inv = 1.0f / s2v;
    const float F1 = -(float)N_ * 1.8378770664093453f      // N*log(2*pi)
                   - (float)(N_ - M_) * logf(s2v)
                   + (ld1 - ld2)
                   - YY * inv
                   + quad * inv
                   - (float)N_ * sf * sf * inv
                   + tr * inv;
    out[0] = 0.5f * (F1 + KL);
  }
}

extern "C" void kernel_launch(void* const* d_in, const int* in_sizes, int n_in,
                              void* d_out, int out_size, void* d_ws, size_t ws_size,
                              hipStream_t stream) {
  const float* X    = (const float*)d_in[0];
  const float* Y    = (const float*)d_in[1];
  const float* qmu  = (const float*)d_in[2];
  const float* qcov = (const float*)d_in[3];
  const float* Z    = (const float*)d_in[4];
  const float* sfp  = (const float*)d_in[5];
  const float* nvp  = (const float*)d_in[6];
  float* ws  = (float*)d_ws;
  float* out = (float*)d_out;

  vdmgp_mega<<<dim3(16, 18), 256, 0, stream>>>(X, Y, qmu, qcov, Z, ws);
  vdmgp_final<<<1, 256, 0, stream>>>(Z, sfp, nvp, ws, out);
}